// Round 9
// baseline (93.448 us; speedup 1.0000x reference)
//
#include <hip/hip_runtime.h>

#define L_TOTAL   32768
#define E_DIM     64
#define K_TOTAL   1024
#define NT_TOTAL  64                  // K_TOTAL / 16
#define OUT_STRIDE 2097152            // L_TOTAL * E_DIM
#define XPAD      68                  // fp32 x-tile LDS pitch (words)

// staging record: per nt = 1280 words (5120 B):
//   [0,256)    kt0 hi frags (64 lanes x 16 B)
//   [256,512)  kt1 hi
//   [512,768)  kt0 lo
//   [768,1024) kt1 lo
//   [1024,1088) norms (64 f32, dup x4 over quads)
//   [1088,1280) pad
#define NT_WORDS  1280
#define REP       8                   // codebook replicas (L2 line spread)
#define REP_WORDS (NT_TOTAL * NT_WORDS)   // 81920 words = 320 KB per copy

typedef _Float16 half_t;
typedef _Float16 half8  __attribute__((ext_vector_type(8)));
typedef float    floatx4 __attribute__((ext_vector_type(4)));

// ---------------------------------------------------------------------------
// Codebook fp32 -> staged records (f16 hi/lo fragments + norms), x8 replicas.
// Fragment (nt,kt,lane) = e[nt*16 + (lane&15)][kt*32 + (lane>>4)*8 .. +8].
// ---------------------------------------------------------------------------
__global__ __launch_bounds__(128)
void vq_swizzle_kernel(const float* __restrict__ emb, float* __restrict__ ebuf) {
    __shared__ float s_p[128];
    __shared__ float s_n[16];
    const int nt   = blockIdx.x;
    const int t    = threadIdx.x;
    const int kt   = t >> 6;
    const int lane = t & 63;
    const int q    = lane >> 4;
    const int ln   = lane & 15;

    const float* src = emb + (size_t)(nt * 16 + ln) * E_DIM + kt * 32 + q * 8;
    float4 v0 = *(const float4*)src;
    float4 v1 = *(const float4*)(src + 4);
    float f[8] = {v0.x, v0.y, v0.z, v0.w, v1.x, v1.y, v1.z, v1.w};

    half8 h, l;
    float s = 0.f;
    #pragma unroll
    for (int j = 0; j < 8; ++j) {
        half_t hh = (half_t)f[j];
        half_t ll = (half_t)(f[j] - (float)hh);
        h[j] = hh;
        l[j] = ll;
        s = fmaf(f[j], f[j], s);
    }
    s_p[t] = s;

    #pragma unroll
    for (int c = 0; c < REP; ++c) {
        float* rec = ebuf + (size_t)c * REP_WORDS + (size_t)nt * NT_WORDS;
        *(half8*)(rec + kt * 256 + lane * 4)       = h;   // hi
        *(half8*)(rec + 512 + kt * 256 + lane * 4) = l;   // lo
    }

    __syncthreads();
    if (t < 16) {
        float n = 0.f;
        #pragma unroll
        for (int u = 0; u < 8; ++u)
            n += s_p[(u >> 2) * 64 + (u & 3) * 16 + t];
        s_n[t] = n;
    }
    __syncthreads();
    if (t < 64) {
        #pragma unroll
        for (int c = 0; c < REP; ++c)
            ebuf[(size_t)c * REP_WORDS + (size_t)nt * NT_WORDS + 1024 + t] = s_n[t & 15];
    }
}

// ---------------------------------------------------------------------------
// Fused distances + argmin + epilogue. Depth-2 register pipeline (3 buffers),
// norms preloaded, no spill (launch_bounds(256,3) -> ~170 VGPR cap for ~150
// demand). Grid 1024 x 256: block = 4 waves over the SAME 32 latents; wave
// ks scans K-quarter [ks*256,+256) = 16 nt, rotated per block; block reads
// codebook replica blockIdx&7. Lexicographic (dist,index) argmin ==
// numpy first-occurrence, order-independent.
// ---------------------------------------------------------------------------
__global__ __launch_bounds__(256, 3)
void vq_fused_kernel(const float* __restrict__ x,
                     const float* __restrict__ emb,
                     const float* __restrict__ ebuf,
                     float* __restrict__ out) {
    __shared__ float s_x[32 * XPAD];   // 8704 B fp32 x tile
    __shared__ float s_best[4][32];
    __shared__ int   s_bidx[4][32];
    __shared__ int   s_fin[32];

    const int tid   = threadIdx.x;
    const int ks    = tid >> 6;        // K-split wave 0..3
    const int lane  = tid & 63;
    const int q     = lane >> 4;
    const int ln    = lane & 15;
    const int mbase = blockIdx.x * 32;
    const int rot   = blockIdx.x & 15;
    const int nt0   = ks * 16;
    const float* eb = ebuf + (size_t)(blockIdx.x & (REP - 1)) * REP_WORDS;

#define NTI(J) (nt0 + (((J) + rot) & 15))
#define LOADB(B0, B1, B2, B3, J) {                                            \
        const float* rec_ = eb + (size_t)NTI(J) * NT_WORDS;                   \
        B0 = *(const half8*)(rec_ + lane * 4);                                \
        B1 = *(const half8*)(rec_ + 256 + lane * 4);                          \
        B2 = *(const half8*)(rec_ + 512 + lane * 4);                          \
        B3 = *(const half8*)(rec_ + 768 + lane * 4); }

    // ---- issue first 3 buffer loads + all 16 norm loads up front
    half8 a0, a1, a2, a3, b0, b1, b2, b3, c0, c1, c2, c3;
    LOADB(a0, a1, a2, a3, 0)
    LOADB(b0, b1, b2, b3, 1)
    LOADB(c0, c1, c2, c3, 2)
    float nv[16];
    #pragma unroll
    for (int j = 0; j < 16; ++j)
        nv[j] = eb[(size_t)NTI(j) * NT_WORDS + 1024 + lane];

    // ---- stage x tile: coalesced float4 -> padded LDS (2 per thread)
    {
        const float4* xg = (const float4*)(x + (size_t)mbase * E_DIM);
        #pragma unroll
        for (int i = 0; i < 2; ++i) {
            const int f   = i * 256 + tid;       // 0..511 float4 of tile
            const int row = f >> 4;
            const int col = (f & 15) * 4;
            *(float4*)(&s_x[row * XPAD + col]) = xg[f];
        }
    }
    __syncthreads();

    // ---- A fragments (hi/lo) + row norms for the block's 32 latents
    half8 A[2][2][2];                  // [rt][kt][hi/lo]  = 32 VGPRs
    floatx4 xq[2];
    #pragma unroll
    for (int rt = 0; rt < 2; ++rt) {
        const float* xr = &s_x[(rt * 16 + ln) * XPAD + q * 8];
        float sn = 0.f;
        #pragma unroll
        for (int kt = 0; kt < 2; ++kt) {
            float4 v0 = *(const float4*)(xr + kt * 32);
            float4 v1 = *(const float4*)(xr + kt * 32 + 4);
            float f[8] = {v0.x, v0.y, v0.z, v0.w, v1.x, v1.y, v1.z, v1.w};
            #pragma unroll
            for (int j = 0; j < 8; ++j) {
                half_t hh = (half_t)f[j];
                half_t ll = (half_t)(f[j] - (float)hh);
                A[rt][kt][0][j] = hh;
                A[rt][kt][1][j] = ll;
                sn = fmaf(f[j], f[j], sn);
            }
        }
        sn += __shfl_xor(sn, 16, 64);
        sn += __shfl_xor(sn, 32, 64);
        #pragma unroll
        for (int r = 0; r < 4; ++r)
            xq[rt][r] = __shfl(sn, q * 4 + r, 64);
    }

    float best[2][4];
    int   bidx[2][4];
    #pragma unroll
    for (int rt = 0; rt < 2; ++rt)
        #pragma unroll
        for (int r = 0; r < 4; ++r) { best[rt][r] = 3.402823466e+38f; bidx[rt][r] = 0x7fffffff; }

#define STEP(B0, B1, B2, B3, J) {                                             \
        const int nt_ = NTI(J);                                               \
        const int kg_ = nt_ * 16 + ln;                                        \
        const float env_ = nv[J];                                             \
        _Pragma("unroll")                                                     \
        for (int rt = 0; rt < 2; ++rt) {                                      \
            floatx4 Ca = {0.f, 0.f, 0.f, 0.f};                                \
            floatx4 Cb = {0.f, 0.f, 0.f, 0.f};                                \
            Ca = __builtin_amdgcn_mfma_f32_16x16x32_f16(A[rt][0][0], B0, Ca, 0, 0, 0); \
            Ca = __builtin_amdgcn_mfma_f32_16x16x32_f16(A[rt][1][0], B1, Ca, 0, 0, 0); \
            Cb = __builtin_amdgcn_mfma_f32_16x16x32_f16(A[rt][0][1], B0, Cb, 0, 0, 0); \
            Cb = __builtin_amdgcn_mfma_f32_16x16x32_f16(A[rt][1][1], B1, Cb, 0, 0, 0); \
            Cb = __builtin_amdgcn_mfma_f32_16x16x32_f16(A[rt][0][0], B2, Cb, 0, 0, 0); \
            Cb = __builtin_amdgcn_mfma_f32_16x16x32_f16(A[rt][1][0], B3, Cb, 0, 0, 0); \
            _Pragma("unroll")                                                 \
            for (int r = 0; r < 4; ++r) {                                     \
                float dot = Ca[r] + Cb[r];                                    \
                float d = __fadd_rn(__fsub_rn(xq[rt][r], __fmul_rn(2.0f, dot)), env_); \
                if (d < best[rt][r] || (d == best[rt][r] && kg_ < bidx[rt][r])) {      \
                    best[rt][r] = d; bidx[rt][r] = kg_;                       \
                }                                                             \
            }                                                                 \
        } }

    // ---- 16-step scan, 3-buffer rotation, loads 2 steps ahead
    STEP(a0, a1, a2, a3, 0)  LOADB(a0, a1, a2, a3, 3)
    STEP(b0, b1, b2, b3, 1)  LOADB(b0, b1, b2, b3, 4)
    STEP(c0, c1, c2, c3, 2)  LOADB(c0, c1, c2, c3, 5)
    STEP(a0, a1, a2, a3, 3)  LOADB(a0, a1, a2, a3, 6)
    STEP(b0, b1, b2, b3, 4)  LOADB(b0, b1, b2, b3, 7)
    STEP(c0, c1, c2, c3, 5)  LOADB(c0, c1, c2, c3, 8)
    STEP(a0, a1, a2, a3, 6)  LOADB(a0, a1, a2, a3, 9)
    STEP(b0, b1, b2, b3, 7)  LOADB(b0, b1, b2, b3, 10)
    STEP(c0, c1, c2, c3, 8)  LOADB(c0, c1, c2, c3, 11)
    STEP(a0, a1, a2, a3, 9)  LOADB(a0, a1, a2, a3, 12)
    STEP(b0, b1, b2, b3, 10) LOADB(b0, b1, b2, b3, 13)
    STEP(c0, c1, c2, c3, 11) LOADB(c0, c1, c2, c3, 14)
    STEP(a0, a1, a2, a3, 12) LOADB(a0, a1, a2, a3, 15)
    STEP(b0, b1, b2, b3, 13)
    STEP(c0, c1, c2, c3, 14)
    STEP(a0, a1, a2, a3, 15)

#undef STEP
#undef LOADB
#undef NTI

    // ---- argmin across the 16 col-lanes of each quad (ties -> lower index)
    #pragma unroll
    for (int o = 1; o < 16; o <<= 1) {
        #pragma unroll
        for (int rt = 0; rt < 2; ++rt)
            #pragma unroll
            for (int r = 0; r < 4; ++r) {
                float ob = __shfl_xor(best[rt][r], o, 64);
                int   oi = __shfl_xor(bidx[rt][r], o, 64);
                if (ob < best[rt][r] || (ob == best[rt][r] && oi < bidx[rt][r])) {
                    best[rt][r] = ob; bidx[rt][r] = oi;
                }
            }
    }
    if (ln == 0) {
        #pragma unroll
        for (int rt = 0; rt < 2; ++rt)
            #pragma unroll
            for (int r = 0; r < 4; ++r) {
                s_best[ks][rt * 16 + q * 4 + r] = best[rt][r];
                s_bidx[ks][rt * 16 + q * 4 + r] = bidx[rt][r];
            }
    }
    __syncthreads();

    // ---- merge the 4 K-splits (lexicographic == first-occurrence)
    if (tid < 32) {
        float b = 3.402823466e+38f;
        int   i = 0x7fffffff;
        #pragma unroll
        for (int s = 0; s < 4; ++s) {
            float pb = s_best[s][tid];
            int   pi = s_bidx[s][tid];
            if (pb < b || (pb == b && pi < i)) { b = pb; i = pi; }
        }
        s_fin[tid] = i;
        out[3 * (size_t)OUT_STRIDE + mbase + tid] = (float)i;   // coalesced
    }
    __syncthreads();

    // ---- coalesced epilogue over the 32x64 tile:
    // out0 = exact x (LDS), out1 = emb[idx], out2 = (x + q) - x.
    {
        const size_t fb = (size_t)mbase * (E_DIM / 4);
        float4* o0 = (float4*)out + fb;
        float4* o1 = (float4*)(out + OUT_STRIDE) + fb;
        float4* o2 = (float4*)(out + 2 * (size_t)OUT_STRIDE) + fb;
        #pragma unroll
        for (int i = 0; i < 2; ++i) {
            const int f   = i * 256 + tid;       // 0..511
            const int row = f >> 4;
            const int col = (f & 15) * 4;
            const float4 xv = *(const float4*)(&s_x[row * XPAD + col]);
            const int idx = s_fin[row];
            const float4 qv = *(const float4*)(emb + (size_t)idx * E_DIM + col);
            float4 z;
            z.x = __fsub_rn(__fadd_rn(xv.x, qv.x), xv.x);
            z.y = __fsub_rn(__fadd_rn(xv.y, qv.y), xv.y);
            z.z = __fsub_rn(__fadd_rn(xv.z, qv.z), xv.z);
            z.w = __fsub_rn(__fadd_rn(xv.w, qv.w), xv.w);
            o0[f] = xv;
            o1[f] = qv;
            o2[f] = z;
        }
    }
}

// ---------------------------------------------------------------------------
extern "C" void kernel_launch(void* const* d_in, const int* in_sizes, int n_in,
                              void* d_out, int out_size, void* d_ws, size_t ws_size,
                              hipStream_t stream) {
    const float* x   = (const float*)d_in[0];
    const float* emb = (const float*)d_in[1];
    float* out  = (float*)d_out;
    float* ebuf = (float*)d_ws;   // 8 replicas x 320 KB = 2.6 MB staged codebook

    hipLaunchKernelGGL(vq_swizzle_kernel, dim3(NT_TOTAL), dim3(128), 0, stream,
                       emb, ebuf);
    hipLaunchKernelGGL(vq_fused_kernel, dim3(L_TOTAL / 32), dim3(256), 0, stream,
                       x, emb, ebuf, out);
}